// Round 12
// baseline (541.623 us; speedup 1.0000x reference)
//
#include <hip/hip_runtime.h>

// WindowAttention v12 for MI355X (gfx950) — 4-kernel short-chain pipeline.
// B=4096, N=49, C=256, H=8, hd=32. fp32 in/out, f16 MFMA inside.
//
// v11 lesson: wa_qkv at launch_bounds(512,5) got VGPR=40 -> loads serialize,
// all pipes idle, 353us for a GEMM wa_proj's structure does in ~55us.
// v12: wa_qkv is a clone of the PROVEN wa_proj shape: 128-row tiles, grid
// (1568,3), __launch_bounds__(512) (no reg cap), acc[2][8], and GEMM-natural
// row-major output [b*49+tok][h*32+d] (no /49 scatter in the epilogue).
// wa_attn2 reads q/k/v from the row-major layout (fragments still 16B
// contiguous). wa_proj verbatim.

#define NTOK 49
#define PPAD 264
#define SCALE_F 0.17677669529663687f

typedef _Float16 v8h __attribute__((ext_vector_type(8)));
typedef _Float16 v4h __attribute__((ext_vector_type(4)));
typedef float    v4f __attribute__((ext_vector_type(4)));
typedef int      v4i __attribute__((ext_vector_type(4)));

__device__ __forceinline__ v8h ldsv8(const _Float16* p) { return *(const v8h*)p; }

// ---------------- prep: f16 weights + float4-packed bias rows ----------------
__global__ void wa_prep(const float* __restrict__ Wq, const float* __restrict__ Wk,
                        const float* __restrict__ Wv, const float* __restrict__ Wp,
                        const float* __restrict__ bias_table, const int* __restrict__ rel_idx,
                        _Float16* __restrict__ wqkv, _Float16* __restrict__ wp,
                        float* __restrict__ biasm2) {
    int t = blockIdx.x * blockDim.x + threadIdx.x;
    const int NW = 768 * 256;
    const int NP = 256 * 256;
    const int NB4 = 8 * NTOK * 16;
    if (t < NW) {
        int n = t >> 8, k = t & 255;
        const float* W = (n < 256) ? Wq : (n < 512 ? Wk : Wv);
        wqkv[t] = (_Float16)W[(n & 255) * 256 + k];
    } else if (t < NW + NP) {
        int u = t - NW;
        wp[u] = (_Float16)Wp[u];
    } else if (t < NW + NP + NB4) {
        int u = t - NW - NP;               // (h*49 + row)*16 + fr
        int fr = u & 15;
        int hr = u >> 4;
        int row = hr % NTOK;
        int h = hr / NTOK;
        float4 v;
        float* vp = &v.x;
        #pragma unroll
        for (int c = 0; c < 4; ++c) {
            int col = fr + 16 * c;
            vp[c] = (col < NTOK) ? bias_table[rel_idx[row * NTOK + col] * 8 + h] : 0.f;
        }
        ((float4*)biasm2)[u] = v;
    }
}

// ---------------- K1: qkv GEMM, wa_proj-shaped. grid (1568, 3) ----------------
// Output layout: dst[row][n] f16, row = b*49+tok (0..200703), n = h*32+d.
__global__ __launch_bounds__(512) void wa_qkv(
    const float* __restrict__ x,
    const float* __restrict__ bq, const float* __restrict__ bk,
    const float* __restrict__ bv,
    const _Float16* __restrict__ wqkv,
    _Float16* __restrict__ qg, _Float16* __restrict__ kg, _Float16* __restrict__ vg) {

    __shared__ _Float16 as[128 * PPAD];      // 67,584 B

    const int mb   = blockIdx.x;             // 128-row tile, 1568 exact
    const int y    = blockIdx.y;             // 0:q 1:k 2:v
    const int tid  = threadIdx.x;
    const int wid  = tid >> 6;               // 0..7
    const int lane = tid & 63;
    const int g    = lane >> 4;
    const int fr   = lane & 15;

    // stage 128x256 f32 -> f16 LDS
    const float* xb = x + (size_t)mb * (128 * 256);
    for (int i = tid; i < (128 * 256) / 4; i += 512) {
        float4 f = ((const float4*)xb)[i];
        int e = i * 4;
        v4h pk;
        pk[0] = (_Float16)f.x; pk[1] = (_Float16)f.y;
        pk[2] = (_Float16)f.z; pk[3] = (_Float16)f.w;
        *(v4h*)&as[(e >> 8) * PPAD + (e & 255)] = pk;
    }
    __syncthreads();

    const v4f vzero = {0.f, 0.f, 0.f, 0.f};
    v4f acc[2][8];
    #pragma unroll
    for (int ntl = 0; ntl < 2; ++ntl)
        #pragma unroll
        for (int mt = 0; mt < 8; ++mt) acc[ntl][mt] = vzero;

    #pragma unroll
    for (int ks = 0; ks < 8; ++ks) {
        v8h a[8];
        #pragma unroll
        for (int mt = 0; mt < 8; ++mt)
            a[mt] = ldsv8(&as[(mt * 16 + fr) * PPAD + ks * 32 + g * 8]);
        #pragma unroll
        for (int ntl = 0; ntl < 2; ++ntl) {
            int n = y * 256 + wid * 32 + 16 * ntl + fr;
            v8h bf = *(const v8h*)&wqkv[n * 256 + ks * 32 + g * 8];
            #pragma unroll
            for (int mt = 0; mt < 8; ++mt)
                acc[ntl][mt] = __builtin_amdgcn_mfma_f32_16x16x32_f16(a[mt], bf, acc[ntl][mt], 0, 0, 0);
        }
    }

    const float* bias_p = (y == 0) ? bq : (y == 1) ? bk : bv;
    const float  scl    = (y == 0) ? SCALE_F : 1.f;
    _Float16*    dst    = (y == 0) ? qg : (y == 1) ? kg : vg;
    _Float16* ob = dst + (size_t)mb * (128 * 256);
    #pragma unroll
    for (int ntl = 0; ntl < 2; ++ntl) {
        int n = wid * 32 + 16 * ntl + fr;
        float bn = bias_p[n];
        #pragma unroll
        for (int mt = 0; mt < 8; ++mt)
            #pragma unroll
            for (int r = 0; r < 4; ++r)
                ob[(mt * 16 + 4 * g + r) * 256 + n] = (_Float16)((acc[ntl][mt][r] + bn) * scl);
    }
}

// ---------------- K2: attention, 1 wave = 1 (window,head), NO barriers ----------------
#define AW (32 * 64 + NTOK * 64)   // per-wave arena halfs: vT[32][64] + P[49][64] = 5184
__global__ __launch_bounds__(256, 4) void wa_attn2(
    const _Float16* __restrict__ qg, const _Float16* __restrict__ kg,
    const _Float16* __restrict__ vg, const float* __restrict__ biasm2,
    _Float16* __restrict__ ao) {

    __shared__ _Float16 arena[4 * AW];       // 41,472 B -> 3 blocks/CU

    const int tid  = threadIdx.x;
    const int wid  = tid >> 6;
    const int lane = tid & 63;
    const int g    = lane >> 4;
    const int fr   = lane & 15;
    const int bh   = blockIdx.x * 4 + wid;   // 0..32767
    const int b    = bh >> 3, h = bh & 7;

    _Float16* vT = &arena[wid * AW];         // [32][64], XOR-swizzled tok
    _Float16* P  = vT + 32 * 64;             // [49][64], v8 swizzle

    // row-major qkv: row = b*49+tok, col = h*32+d
    const _Float16* qb = qg + ((size_t)b * NTOK) * 256 + h * 32;
    const _Float16* kb = kg + ((size_t)b * NTOK) * 256 + h * 32;
    const _Float16* vb = vg + ((size_t)b * NTOK) * 256 + h * 32;

    // ---- stage v -> vT[d][tok ^ ((d&7)<<3)], zero-pad toks 49..63 ----
    const v4i izero = {0, 0, 0, 0};
    #pragma unroll
    for (int it = 0; it < 4; ++it) {
        int idx = it * 64 + lane;            // 256 slots of 8 halfs = [64 tok][4 d-groups]
        int tok = idx >> 2;                  // 0..63
        int d0  = (idx & 3) * 8;
        v8h v = __builtin_bit_cast(v8h, izero);
        if (tok < NTOK) v = *(const v8h*)&vb[tok * 256 + d0];
        #pragma unroll
        for (int j = 0; j < 8; ++j)
            vT[(d0 + j) * 64 + (tok ^ (j << 3))] = v[j];
    }

    // ---- q,k fragments straight from global ----
    v8h aq[4], bk4[4];
    #pragma unroll
    for (int t = 0; t < 4; ++t) {
        int row = t * 16 + fr; row = row > 48 ? 48 : row;
        aq[t]  = *(const v8h*)&qb[row * 256 + g * 8];
        bk4[t] = *(const v8h*)&kb[row * 256 + g * 8];
    }

    // ---- QK^T + softmax + P (pre-normalized), per-mt ----
    const v4f vzero = {0.f, 0.f, 0.f, 0.f};
    #pragma unroll
    for (int mt = 0; mt < 4; ++mt) {
        v4f s[4];
        #pragma unroll
        for (int nt = 0; nt < 4; ++nt)
            s[nt] = __builtin_amdgcn_mfma_f32_16x16x32_f16(aq[mt], bk4[nt], vzero, 0, 0, 0);
        #pragma unroll
        for (int r = 0; r < 4; ++r) {
            int row  = mt * 16 + 4 * g + r;
            int brow = row > 48 ? 48 : row;
            float4 b4 = ((const float4*)biasm2)[(h * NTOK + brow) * 16 + fr];
            const float* bp4 = &b4.x;
            // constant-shift softmax (|s+bias| <~ 10): exp(val-12), shift cancels
            float sum = 0.f;
            #pragma unroll
            for (int nt = 0; nt < 4; ++nt) {
                float val = s[nt][r] + bp4[nt];
                if (nt == 3 && fr > 0) val = -1.0e30f;   // col >= 49
                float p = __expf(val - 12.0f);
                s[nt][r] = p;
                sum += p;
            }
            #pragma unroll
            for (int off = 1; off < 16; off <<= 1) sum += __shfl_xor(sum, off);
            float inv = __builtin_amdgcn_rcpf(sum);
            if (row < NTOK) {
                #pragma unroll
                for (int nt = 0; nt < 4; ++nt) {
                    int col = nt * 16 + fr;
                    P[row * 64 + (col ^ ((row & 7) << 3))] = (_Float16)(s[nt][r] * inv);
                }
            }
        }
    }
    // drain in-wave LDS writes (vT + P) before PV reads; wave-private arena
    asm volatile("s_waitcnt lgkmcnt(0)" ::: "memory");
    __builtin_amdgcn_sched_barrier(0);

    // ---- PV ----
    v8h bvf[2][2];
    #pragma unroll
    for (int ks = 0; ks < 2; ++ks)
        #pragma unroll
        for (int ntd = 0; ntd < 2; ++ntd) {
            int d = 16 * ntd + fr;
            bvf[ks][ntd] = ldsv8(&vT[d * 64 + ((32 * ks + 8 * g) ^ ((d & 7) << 3))]);
        }
    v4f o[4][2];
    #pragma unroll
    for (int mt = 0; mt < 4; ++mt) { o[mt][0] = vzero; o[mt][1] = vzero; }
    #pragma unroll
    for (int mt = 0; mt < 4; ++mt) {
        int row = mt * 16 + fr; row = row > 48 ? 48 : row;
        int r7 = row & 7;
        #pragma unroll
        for (int ks = 0; ks < 2; ++ks) {
            v8h ap = ldsv8(&P[row * 64 + ((4 * ks + g) ^ r7) * 8]);
            #pragma unroll
            for (int ntd = 0; ntd < 2; ++ntd)
                o[mt][ntd] = __builtin_amdgcn_mfma_f32_16x16x32_f16(ap, bvf[ks][ntd], o[mt][ntd], 0, 0, 0);
        }
    }
    // ---- store ao[b*49+tok][h*32+d] f16 ----
    _Float16* ob = ao + ((size_t)b * NTOK) * 256 + h * 32;
    #pragma unroll
    for (int mt = 0; mt < 4; ++mt)
        #pragma unroll
        for (int r = 0; r < 4; ++r) {
            int tok = mt * 16 + 4 * g + r;
            if (tok < NTOK) {
                #pragma unroll
                for (int ntd = 0; ntd < 2; ++ntd)
                    ob[tok * 256 + 16 * ntd + fr] = (_Float16)o[mt][ntd][r];
            }
        }
}

// ---------------- K3: out = ao @ Wp^T + bp (proven, verbatim) ----------------
__global__ __launch_bounds__(512) void wa_proj(
    const _Float16* __restrict__ ao, const _Float16* __restrict__ wp,
    const float* __restrict__ bp, float* __restrict__ out) {

    __shared__ _Float16 as[128 * PPAD];

    const int mb   = blockIdx.x;
    const int tid  = threadIdx.x;
    const int wid  = tid >> 6;
    const int lane = tid & 63;
    const int g    = lane >> 4;
    const int fr   = lane & 15;

    const _Float16* ab = ao + (size_t)mb * (128 * 256);
    for (int i = tid; i < (128 * 256) / 8; i += 512) {
        v8h v = *(const v8h*)&ab[i * 8];
        int e = i * 8;
        *(v8h*)&as[(e >> 8) * PPAD + (e & 255)] = v;
    }
    __syncthreads();

    const v4f vzero = {0.f, 0.f, 0.f, 0.f};
    v4f acc[2][8];
    #pragma unroll
    for (int ntl = 0; ntl < 2; ++ntl)
        #pragma unroll
        for (int mt = 0; mt < 8; ++mt) acc[ntl][mt] = vzero;

    #pragma unroll
    for (int ks = 0; ks < 8; ++ks) {
        v8h a[8];
        #pragma unroll
        for (int mt = 0; mt < 8; ++mt)
            a[mt] = ldsv8(&as[(mt * 16 + fr) * PPAD + ks * 32 + g * 8]);
        #pragma unroll
        for (int ntl = 0; ntl < 2; ++ntl) {
            int n = wid * 32 + 16 * ntl + fr;
            v8h bf = *(const v8h*)&wp[n * 256 + ks * 32 + g * 8];
            #pragma unroll
            for (int mt = 0; mt < 8; ++mt)
                acc[ntl][mt] = __builtin_amdgcn_mfma_f32_16x16x32_f16(a[mt], bf, acc[ntl][mt], 0, 0, 0);
        }
    }

    float* ob = out + (size_t)mb * (128 * 256);
    #pragma unroll
    for (int ntl = 0; ntl < 2; ++ntl) {
        int n = wid * 32 + 16 * ntl + fr;
        float bpn = bp[n];
        #pragma unroll
        for (int mt = 0; mt < 8; ++mt)
            #pragma unroll
            for (int r = 0; r < 4; ++r)
                ob[(mt * 16 + 4 * g + r) * 256 + n] = acc[ntl][mt][r] + bpn;
    }
}

extern "C" void kernel_launch(void* const* d_in, const int* in_sizes, int n_in,
                              void* d_out, int out_size, void* d_ws, size_t ws_size,
                              hipStream_t stream) {
    const float* x          = (const float*)d_in[0];
    const float* bias_table = (const float*)d_in[1];
    const float* Wq         = (const float*)d_in[2];
    const float* bq         = (const float*)d_in[3];
    const float* Wk         = (const float*)d_in[4];
    const float* bk         = (const float*)d_in[5];
    const float* Wv         = (const float*)d_in[6];
    const float* bv         = (const float*)d_in[7];
    const float* Wp         = (const float*)d_in[8];
    const float* bp         = (const float*)d_in[9];
    const int*   rel_idx    = (const int*)d_in[10];
    float* out = (float*)d_out;

    // ws layout (bytes):
    //   wqkv f16 [768*256]      @ 0
    //   wp   f16 [256*256]      @ 393216
    //   biasm2 f32 [8*49*16*4]  @ 524288
    //   qg f16 [200704*256]     @ 624640      (102,760,448 each)
    //   kg                      @ 624640 + 1*102760448
    //   vg                      @ 624640 + 2*102760448
    //   ao f16 [200704*256]     @ 624640 + 3*102760448     total ~411.7 MB
    _Float16* wqkv   = (_Float16*)d_ws;
    _Float16* wp     = wqkv + 768 * 256;
    float*    biasm2 = (float*)(wp + 256 * 256);
    char*     base   = (char*)d_ws + 624640;
    _Float16* qg = (_Float16*)(base);
    _Float16* kg = (_Float16*)(base + 1ull * 102760448);
    _Float16* vg = (_Float16*)(base + 2ull * 102760448);
    _Float16* ao = (_Float16*)(base + 3ull * 102760448);

    const int TOT = 768 * 256 + 256 * 256 + 8 * NTOK * 16;
    wa_prep<<<(TOT + 255) / 256, 256, 0, stream>>>(Wq, Wk, Wv, Wp, bias_table, rel_idx,
                                                   wqkv, wp, biasm2);
    wa_qkv<<<dim3(1568, 3), 512, 0, stream>>>(x, bq, bk, bv, wqkv, qg, kg, vg);
    wa_attn2<<<8192, 256, 0, stream>>>(qg, kg, vg, biasm2, ao);
    wa_proj<<<1568, 512, 0, stream>>>(ao, wp, bp, out);
}

// Round 13
// 461.523 us; speedup vs baseline: 1.1736x; 1.1736x over previous
//
#include <hip/hip_runtime.h>

// WindowAttention v13 for MI355X (gfx950) — 4-kernel short-chain pipeline.
// B=4096, N=49, C=256, H=8, hd=32. fp32 in/out, f16 MFMA inside.
//
// v12 lesson: wa_qkv's acc[2][8] (64 AGPR) + 68 arch = 132/wave -> 1
// block/CU -> serial per-block phase chains, 365us. wa_proj survives 1
// block/CU only because it is HBM-bound per CU (it IS at its roofline).
// v13 wa_qkv: 64-row tiles (acc[2][4]=32 AGPR, ~95 total regs -> 5
// waves/SIMD -> 2 blocks/CU resident -> staging of block i+1 overlaps
// epilogue of block i), grid (3,3136) with qkv-slice fastest so each x-tile's
// 3 reads are temporally adjacent (L2/L3-hot). attn2/proj/prep verbatim.

#define NTOK 49
#define PPAD 264
#define SCALE_F 0.17677669529663687f

typedef _Float16 v8h __attribute__((ext_vector_type(8)));
typedef _Float16 v4h __attribute__((ext_vector_type(4)));
typedef float    v4f __attribute__((ext_vector_type(4)));
typedef int      v4i __attribute__((ext_vector_type(4)));

__device__ __forceinline__ v8h ldsv8(const _Float16* p) { return *(const v8h*)p; }

// ---------------- prep: f16 weights + float4-packed bias rows ----------------
__global__ void wa_prep(const float* __restrict__ Wq, const float* __restrict__ Wk,
                        const float* __restrict__ Wv, const float* __restrict__ Wp,
                        const float* __restrict__ bias_table, const int* __restrict__ rel_idx,
                        _Float16* __restrict__ wqkv, _Float16* __restrict__ wp,
                        float* __restrict__ biasm2) {
    int t = blockIdx.x * blockDim.x + threadIdx.x;
    const int NW = 768 * 256;
    const int NP = 256 * 256;
    const int NB4 = 8 * NTOK * 16;
    if (t < NW) {
        int n = t >> 8, k = t & 255;
        const float* W = (n < 256) ? Wq : (n < 512 ? Wk : Wv);
        wqkv[t] = (_Float16)W[(n & 255) * 256 + k];
    } else if (t < NW + NP) {
        int u = t - NW;
        wp[u] = (_Float16)Wp[u];
    } else if (t < NW + NP + NB4) {
        int u = t - NW - NP;               // (h*49 + row)*16 + fr
        int fr = u & 15;
        int hr = u >> 4;
        int row = hr % NTOK;
        int h = hr / NTOK;
        float4 v;
        float* vp = &v.x;
        #pragma unroll
        for (int c = 0; c < 4; ++c) {
            int col = fr + 16 * c;
            vp[c] = (col < NTOK) ? bias_table[rel_idx[row * NTOK + col] * 8 + h] : 0.f;
        }
        ((float4*)biasm2)[u] = v;
    }
}

// ---------------- K1: qkv GEMM. grid (3, 3136): x = q/k/v slice, y = 64-row tile ----
// Output layout: dst[row][n] f16, row = b*49+tok (0..200703), n = h*32+d.
__global__ __launch_bounds__(512) void wa_qkv(
    const float* __restrict__ x,
    const float* __restrict__ bq, const float* __restrict__ bk,
    const float* __restrict__ bv,
    const _Float16* __restrict__ wqkv,
    _Float16* __restrict__ qg, _Float16* __restrict__ kg, _Float16* __restrict__ vg) {

    __shared__ _Float16 as[64 * PPAD];       // 33,792 B -> 2 blocks/CU

    const int y    = blockIdx.x;             // 0:q 1:k 2:v (fastest -> x tile L2/L3-hot)
    const int mb   = blockIdx.y;             // 64-row tile, 3136 exact
    const int tid  = threadIdx.x;
    const int wid  = tid >> 6;               // 0..7 -> 32-col slice
    const int lane = tid & 63;
    const int g    = lane >> 4;
    const int fr   = lane & 15;

    // stage 64x256 f32 -> f16 LDS (8 float4 per thread)
    const float* xb = x + (size_t)mb * (64 * 256);
    #pragma unroll
    for (int j = 0; j < 8; ++j) {
        int i = tid + j * 512;
        float4 f = ((const float4*)xb)[i];
        int e = i * 4;
        v4h pk;
        pk[0] = (_Float16)f.x; pk[1] = (_Float16)f.y;
        pk[2] = (_Float16)f.z; pk[3] = (_Float16)f.w;
        *(v4h*)&as[(e >> 8) * PPAD + (e & 255)] = pk;
    }
    __syncthreads();

    const v4f vzero = {0.f, 0.f, 0.f, 0.f};
    v4f acc[2][4];
    #pragma unroll
    for (int ntl = 0; ntl < 2; ++ntl)
        #pragma unroll
        for (int mt = 0; mt < 4; ++mt) acc[ntl][mt] = vzero;

    #pragma unroll
    for (int ks = 0; ks < 8; ++ks) {
        v8h a[4];
        #pragma unroll
        for (int mt = 0; mt < 4; ++mt)
            a[mt] = ldsv8(&as[(mt * 16 + fr) * PPAD + ks * 32 + g * 8]);
        #pragma unroll
        for (int ntl = 0; ntl < 2; ++ntl) {
            int n = y * 256 + wid * 32 + 16 * ntl + fr;
            v8h bf = *(const v8h*)&wqkv[n * 256 + ks * 32 + g * 8];
            #pragma unroll
            for (int mt = 0; mt < 4; ++mt)
                acc[ntl][mt] = __builtin_amdgcn_mfma_f32_16x16x32_f16(a[mt], bf, acc[ntl][mt], 0, 0, 0);
        }
    }

    const float* bias_p = (y == 0) ? bq : (y == 1) ? bk : bv;
    const float  scl    = (y == 0) ? SCALE_F : 1.f;
    _Float16*    dst    = (y == 0) ? qg : (y == 1) ? kg : vg;
    _Float16* ob = dst + (size_t)mb * (64 * 256);
    #pragma unroll
    for (int ntl = 0; ntl < 2; ++ntl) {
        int n = wid * 32 + 16 * ntl + fr;
        float bn = bias_p[n];
        #pragma unroll
        for (int mt = 0; mt < 4; ++mt)
            #pragma unroll
            for (int r = 0; r < 4; ++r)
                ob[(mt * 16 + 4 * g + r) * 256 + n] = (_Float16)((acc[ntl][mt][r] + bn) * scl);
    }
}

// ---------------- K2: attention, 1 wave = 1 (window,head), NO barriers ----------------
#define AW (32 * 64 + NTOK * 64)   // per-wave arena halfs: vT[32][64] + P[49][64] = 5184
__global__ __launch_bounds__(256, 4) void wa_attn2(
    const _Float16* __restrict__ qg, const _Float16* __restrict__ kg,
    const _Float16* __restrict__ vg, const float* __restrict__ biasm2,
    _Float16* __restrict__ ao) {

    __shared__ _Float16 arena[4 * AW];       // 41,472 B -> 3 blocks/CU

    const int tid  = threadIdx.x;
    const int wid  = tid >> 6;
    const int lane = tid & 63;
    const int g    = lane >> 4;
    const int fr   = lane & 15;
    const int bh   = blockIdx.x * 4 + wid;   // 0..32767
    const int b    = bh >> 3, h = bh & 7;

    _Float16* vT = &arena[wid * AW];         // [32][64], XOR-swizzled tok
    _Float16* P  = vT + 32 * 64;             // [49][64], v8 swizzle

    // row-major qkv: row = b*49+tok, col = h*32+d
    const _Float16* qb = qg + ((size_t)b * NTOK) * 256 + h * 32;
    const _Float16* kb = kg + ((size_t)b * NTOK) * 256 + h * 32;
    const _Float16* vb = vg + ((size_t)b * NTOK) * 256 + h * 32;

    // ---- stage v -> vT[d][tok ^ ((d&7)<<3)], zero-pad toks 49..63 ----
    const v4i izero = {0, 0, 0, 0};
    #pragma unroll
    for (int it = 0; it < 4; ++it) {
        int idx = it * 64 + lane;            // 256 slots of 8 halfs = [64 tok][4 d-groups]
        int tok = idx >> 2;                  // 0..63
        int d0  = (idx & 3) * 8;
        v8h v = __builtin_bit_cast(v8h, izero);
        if (tok < NTOK) v = *(const v8h*)&vb[tok * 256 + d0];
        #pragma unroll
        for (int j = 0; j < 8; ++j)
            vT[(d0 + j) * 64 + (tok ^ (j << 3))] = v[j];
    }

    // ---- q,k fragments straight from global ----
    v8h aq[4], bk4[4];
    #pragma unroll
    for (int t = 0; t < 4; ++t) {
        int row = t * 16 + fr; row = row > 48 ? 48 : row;
        aq[t]  = *(const v8h*)&qb[row * 256 + g * 8];
        bk4[t] = *(const v8h*)&kb[row * 256 + g * 8];
    }

    // ---- QK^T + softmax + P (pre-normalized), per-mt ----
    const v4f vzero = {0.f, 0.f, 0.f, 0.f};
    #pragma unroll
    for (int mt = 0; mt < 4; ++mt) {
        v4f s[4];
        #pragma unroll
        for (int nt = 0; nt < 4; ++nt)
            s[nt] = __builtin_amdgcn_mfma_f32_16x16x32_f16(aq[mt], bk4[nt], vzero, 0, 0, 0);
        #pragma unroll
        for (int r = 0; r < 4; ++r) {
            int row  = mt * 16 + 4 * g + r;
            int brow = row > 48 ? 48 : row;
            float4 b4 = ((const float4*)biasm2)[(h * NTOK + brow) * 16 + fr];
            const float* bp4 = &b4.x;
            // constant-shift softmax (|s+bias| <~ 10): exp(val-12), shift cancels
            float sum = 0.f;
            #pragma unroll
            for (int nt = 0; nt < 4; ++nt) {
                float val = s[nt][r] + bp4[nt];
                if (nt == 3 && fr > 0) val = -1.0e30f;   // col >= 49
                float p = __expf(val - 12.0f);
                s[nt][r] = p;
                sum += p;
            }
            #pragma unroll
            for (int off = 1; off < 16; off <<= 1) sum += __shfl_xor(sum, off);
            float inv = __builtin_amdgcn_rcpf(sum);
            if (row < NTOK) {
                #pragma unroll
                for (int nt = 0; nt < 4; ++nt) {
                    int col = nt * 16 + fr;
                    P[row * 64 + (col ^ ((row & 7) << 3))] = (_Float16)(s[nt][r] * inv);
                }
            }
        }
    }
    // drain in-wave LDS writes (vT + P) before PV reads; wave-private arena
    asm volatile("s_waitcnt lgkmcnt(0)" ::: "memory");
    __builtin_amdgcn_sched_barrier(0);

    // ---- PV ----
    v8h bvf[2][2];
    #pragma unroll
    for (int ks = 0; ks < 2; ++ks)
        #pragma unroll
        for (int ntd = 0; ntd < 2; ++ntd) {
            int d = 16 * ntd + fr;
            bvf[ks][ntd] = ldsv8(&vT[d * 64 + ((32 * ks + 8 * g) ^ ((d & 7) << 3))]);
        }
    v4f o[4][2];
    #pragma unroll
    for (int mt = 0; mt < 4; ++mt) { o[mt][0] = vzero; o[mt][1] = vzero; }
    #pragma unroll
    for (int mt = 0; mt < 4; ++mt) {
        int row = mt * 16 + fr; row = row > 48 ? 48 : row;
        int r7 = row & 7;
        #pragma unroll
        for (int ks = 0; ks < 2; ++ks) {
            v8h ap = ldsv8(&P[row * 64 + ((4 * ks + g) ^ r7) * 8]);
            #pragma unroll
            for (int ntd = 0; ntd < 2; ++ntd)
                o[mt][ntd] = __builtin_amdgcn_mfma_f32_16x16x32_f16(ap, bvf[ks][ntd], o[mt][ntd], 0, 0, 0);
        }
    }
    // ---- store ao[b*49+tok][h*32+d] f16 ----
    _Float16* ob = ao + ((size_t)b * NTOK) * 256 + h * 32;
    #pragma unroll
    for (int mt = 0; mt < 4; ++mt)
        #pragma unroll
        for (int r = 0; r < 4; ++r) {
            int tok = mt * 16 + 4 * g + r;
            if (tok < NTOK) {
                #pragma unroll
                for (int ntd = 0; ntd < 2; ++ntd)
                    ob[tok * 256 + 16 * ntd + fr] = (_Float16)o[mt][ntd][r];
            }
        }
}

// ---------------- K3: out = ao @ Wp^T + bp (proven, verbatim) ----------------
__global__ __launch_bounds__(512) void wa_proj(
    const _Float16* __restrict__ ao, const _Float16* __restrict__ wp,
    const float* __restrict__ bp, float* __restrict__ out) {

    __shared__ _Float16 as[128 * PPAD];

    const int mb   = blockIdx.x;
    const int tid  = threadIdx.x;
    const int wid  = tid >> 6;
    const int lane = tid & 63;
    const int g    = lane >> 4;
    const int fr   = lane & 15;

    const _Float16* ab = ao + (size_t)mb * (128 * 256);
    for (int i = tid; i < (128 * 256) / 8; i += 512) {
        v8h v = *(const v8h*)&ab[i * 8];
        int e = i * 8;
        *(v8h*)&as[(e >> 8) * PPAD + (e & 255)] = v;
    }
    __syncthreads();

    const v4f vzero = {0.f, 0.f, 0.f, 0.f};
    v4f acc[2][8];
    #pragma unroll
    for (int ntl = 0; ntl < 2; ++ntl)
        #pragma unroll
        for (int mt = 0; mt < 8; ++mt) acc[ntl][mt] = vzero;

    #pragma unroll
    for (int ks = 0; ks < 8; ++ks) {
        v8h a[8];
        #pragma unroll
        for (int mt = 0; mt < 8; ++mt)
            a[mt] = ldsv8(&as[(mt * 16 + fr) * PPAD + ks * 32 + g * 8]);
        #pragma unroll
        for (int ntl = 0; ntl < 2; ++ntl) {
            int n = wid * 32 + 16 * ntl + fr;
            v8h bf = *(const v8h*)&wp[n * 256 + ks * 32 + g * 8];
            #pragma unroll
            for (int mt = 0; mt < 8; ++mt)
                acc[ntl][mt] = __builtin_amdgcn_mfma_f32_16x16x32_f16(a[mt], bf, acc[ntl][mt], 0, 0, 0);
        }
    }

    float* ob = out + (size_t)mb * (128 * 256);
    #pragma unroll
    for (int ntl = 0; ntl < 2; ++ntl) {
        int n = wid * 32 + 16 * ntl + fr;
        float bpn = bp[n];
        #pragma unroll
        for (int mt = 0; mt < 8; ++mt)
            #pragma unroll
            for (int r = 0; r < 4; ++r)
                ob[(mt * 16 + 4 * g + r) * 256 + n] = acc[ntl][mt][r] + bpn;
    }
}

extern "C" void kernel_launch(void* const* d_in, const int* in_sizes, int n_in,
                              void* d_out, int out_size, void* d_ws, size_t ws_size,
                              hipStream_t stream) {
    const float* x          = (const float*)d_in[0];
    const float* bias_table = (const float*)d_in[1];
    const float* Wq         = (const float*)d_in[2];
    const float* bq         = (const float*)d_in[3];
    const float* Wk         = (const float*)d_in[4];
    const float* bk         = (const float*)d_in[5];
    const float* Wv         = (const float*)d_in[6];
    const float* bv         = (const float*)d_in[7];
    const float* Wp         = (const float*)d_in[8];
    const float* bp         = (const float*)d_in[9];
    const int*   rel_idx    = (const int*)d_in[10];
    float* out = (float*)d_out;

    // ws layout (bytes):
    //   wqkv f16 [768*256]      @ 0
    //   wp   f16 [256*256]      @ 393216
    //   biasm2 f32 [8*49*16*4]  @ 524288
    //   qg f16 [200704*256]     @ 624640      (102,760,448 each)
    //   kg                      @ 624640 + 1*102760448
    //   vg                      @ 624640 + 2*102760448
    //   ao f16 [200704*256]     @ 624640 + 3*102760448     total ~411.7 MB
    _Float16* wqkv   = (_Float16*)d_ws;
    _Float16* wp     = wqkv + 768 * 256;
    float*    biasm2 = (float*)(wp + 256 * 256);
    char*     base   = (char*)d_ws + 624640;
    _Float16* qg = (_Float16*)(base);
    _Float16* kg = (_Float16*)(base + 1ull * 102760448);
    _Float16* vg = (_Float16*)(base + 2ull * 102760448);
    _Float16* ao = (_Float16*)(base + 3ull * 102760448);

    const int TOT = 768 * 256 + 256 * 256 + 8 * NTOK * 16;
    wa_prep<<<(TOT + 255) / 256, 256, 0, stream>>>(Wq, Wk, Wv, Wp, bias_table, rel_idx,
                                                   wqkv, wp, biasm2);
    wa_qkv<<<dim3(3, 3136), 512, 0, stream>>>(x, bq, bk, bv, wqkv, qg, kg, vg);
    wa_attn2<<<8192, 256, 0, stream>>>(qg, kg, vg, biasm2, ao);
    wa_proj<<<1568, 512, 0, stream>>>(ao, wp, bp, out);
}